// Round 8
// baseline (8794.380 us; speedup 1.0000x reference)
//
#include <hip/hip_runtime.h>
#include <hip/hip_bf16.h>

// Problem constants
#define BB 32    // batch
#define TT 128   // T_E == T_D
#define HH 256   // hidden

__device__ __forceinline__ float rcp_f(float x) { return __builtin_amdgcn_rcpf(x); }
__device__ __forceinline__ float sigmoid_f(float x) {
    return rcp_f(1.f + __expf(-x));  // ~1e-7 rel err vs 7e-3 threshold
}
__device__ __forceinline__ float tanh_f(float x) {
    float e = __expf(2.f * x);
    return 1.f - 2.f * rcp_f(e + 1.f);
}

// LDS-only barrier: orders h_lds/g_lds (LDS) without draining the hs[] global
// store queue (no vmcnt(0)). R16 proved semantic sufficiency of this pattern;
// here it matters because there is no RTT window to hide the store drain in.
__device__ __forceinline__ void bar_lds() {
    asm volatile("s_waitcnt lgkmcnt(0)\n\ts_barrier" ::: "memory");
}

// ---------------------------------------------------------------------------
// LSTM — R23: single block per batch, weights register-resident, SPILL FIXED.
// grid = 32 (block = batch); block = 1024 = 16 waves; thread = one gate row.
// R22 post-mortem: VGPR_Count=64 + WRITE_SIZE=214MB => the single w[64]
// float4 array (1KB) exceeded LLVM's aggregate-promotion threshold and went
// to SCRATCH (6338us). R15's w[32] (512B) has always promoted. Fix: FOUR
// arrays of 16 float4 (256B each), macro-expanded static-index loads/dot.
// Also: encoder/decoder as separate loops (simple live ranges), and
// lgkmcnt-only barriers (no vmcnt drain of the hs store on the chain).
// Per-step chain: VALU 2048cy (1024 thr x 256 FMA @128/cy/CU) + act ~300 +
// 2 barriers ~200; broadcast ds_reads overlap on DS pipe => ~2600cy/step
// vs R15's 4540 (60% mbox RTT). No cross-block exchange exists at all.
// Ledger: R15 484 (RTT-bound) | R16 NULL | R17 706 | R18 589 | R19 NULL |
//   R20 658 | R21 1923 (L2-stream wall) | R22 6338 (scratch spill).
// Pre-commit: VGPR<200 or WRITE>50MB => scratch again => restore R19 and
// declare practical floor. lstm>=484 despite clean promotion => same.
// ---------------------------------------------------------------------------

#define LOADW(Whh)                                                            \
    {                                                                         \
        const float4* _src = (const float4*)((Whh) + tid * HH);               \
        _Pragma("unroll") for (int i = 0; i < 16; ++i) w0[i] = _src[i];       \
        _Pragma("unroll") for (int i = 0; i < 16; ++i) w1[i] = _src[16 + i];  \
        _Pragma("unroll") for (int i = 0; i < 16; ++i) w2[i] = _src[32 + i];  \
        _Pragma("unroll") for (int i = 0; i < 16; ++i) w3[i] = _src[48 + i];  \
    }

#define FMA4(A, W, HV)                 \
    A.x = fmaf(W.x, HV.x, A.x);        \
    A.y = fmaf(W.y, HV.y, A.y);        \
    A.z = fmaf(W.z, HV.z, A.z);        \
    A.w = fmaf(W.w, HV.w, A.w);

#define LSTM_STEP(T_IDX)                                                      \
    {                                                                         \
        const int _t = (T_IDX);                                               \
        const float4* _h4 = (const float4*)h_lds;                             \
        float4 _a = make_float4(0.f, 0.f, 0.f, 0.f);                          \
        _Pragma("unroll") for (int i = 0; i < 16; ++i) {                      \
            float4 hv = _h4[i];       /* broadcast: same addr on all lanes */ \
            FMA4(_a, w0[i], hv)                                               \
        }                                                                     \
        _Pragma("unroll") for (int i = 0; i < 16; ++i) {                      \
            float4 hv = _h4[16 + i];                                          \
            FMA4(_a, w1[i], hv)                                               \
        }                                                                     \
        _Pragma("unroll") for (int i = 0; i < 16; ++i) {                      \
            float4 hv = _h4[32 + i];                                          \
            FMA4(_a, w2[i], hv)                                               \
        }                                                                     \
        _Pragma("unroll") for (int i = 0; i < 16; ++i) {                      \
            float4 hv = _h4[48 + i];                                          \
            FMA4(_a, w3[i], hv)                                               \
        }                                                                     \
        g_lds[tid] = (_a.x + _a.y) + (_a.z + _a.w);                           \
        bar_lds(); /* (A) gates complete; h_lds consumed */                   \
        if (tid < HH) {                                                       \
            const float x = x_lds[_t];                                        \
            float gi = g_lds[tid] + bact[0] + x * wact[0];                    \
            float gf = g_lds[HH + tid] + bact[1] + x * wact[1];               \
            float gg = g_lds[2 * HH + tid] + bact[2] + x * wact[2];           \
            float go = g_lds[3 * HH + tid] + bact[3] + x * wact[3];           \
            float si = sigmoid_f(gi);                                         \
            float sf = sigmoid_f(gf);                                         \
            float tg = tanh_f(gg);                                            \
            float so = sigmoid_f(go);                                         \
            c = sf * c + si * tg;                                             \
            float h = so * tanh_f(c);                                         \
            if (_t < TT && _t == last) { csv = c; hsv = h; }                  \
            hs[((size_t)b * 2 * TT + _t) * HH + tid] = h;                     \
            h_lds[tid] = (_t == TT - 1) ? hsv : h;                            \
        }                                                                     \
        bar_lds(); /* (B) h_lds ready for next dot */                         \
    }

__global__ __launch_bounds__(1024, 4) void lstm_kernel(
    const float* __restrict__ seq,     // [B][128]
    const int* __restrict__ seq_m,     // [B]
    const float* __restrict__ target,  // [B][128]
    const float* __restrict__ Wih_e,   // [1024]
    const float* __restrict__ Whh_e,   // [1024][256]
    const float* __restrict__ bih_e, const float* __restrict__ bhh_e,
    const float* __restrict__ Wih_d, const float* __restrict__ Whh_d,
    const float* __restrict__ bih_d, const float* __restrict__ bhh_d,
    float* __restrict__ hs)  // [B][2T][H] h history (proj kernel input)
{
    const int b = blockIdx.x;
    const int tid = threadIdx.x;  // gate row 0..1023 (i:0-255, f, g, o:768-1023)
    const int last = seq_m[b] - 1;

    __shared__ float h_lds[HH];
    __shared__ float g_lds[4 * HH];
    __shared__ float x_lds[2 * TT];

    for (int i = tid; i < 2 * TT; i += 1024)
        x_lds[i] = (i < TT) ? seq[b * TT + i] : target[b * TT + (i - TT)];

    // act-role constants (threads 0..255, unit u = tid)
    float bact[4], wact[4];
    auto loadact = [&](const float* Wih, const float* bih, const float* bhh) {
        if (tid < HH) {
#pragma unroll
            for (int k = 0; k < 4; ++k) {
                const int r = k * HH + tid;
                bact[k] = bih[r] + bhh[r];
                wact[k] = Wih[r];
            }
        }
    };
    loadact(Wih_e, bih_e, bhh_e);

    if (tid < 64) ((float4*)h_lds)[tid] = make_float4(0.f, 0.f, 0.f, 0.f);
    __syncthreads();

    float c = 0.f, csv = 0.f, hsv = 0.f;

    // full Whh row in registers: 4 x 16 float4 (256B arrays promote cleanly)
    float4 w0[16], w1[16], w2[16], w3[16];

    // ---- encoder ----
    LOADW(Whh_e);
    for (int t = 0; t < TT; ++t) LSTM_STEP(t);

    // ---- encoder -> decoder transition (one-time reg reload, ~1MB L2) ----
    LOADW(Whh_d);
    loadact(Wih_d, bih_d, bhh_d);
    c = csv;  // h_lds already holds hsv (set at t = TT-1)

    // ---- decoder ----
    for (int t = TT; t < 2 * TT; ++t) LSTM_STEP(t);
}

// ---------------------------------------------------------------------------
// Projections: e2 = hs_e @ We^T + be ; d2 = hs_d @ Wd^T + bd.
// grid = 256 = b(32) x 8 t-tiles(32 rows over 2T); block = 256 (thread = col).
// (verified correct in R21/R22 runs)
// ---------------------------------------------------------------------------
__global__ __launch_bounds__(256) void proj_kernel(
    const float* __restrict__ hs, const float* __restrict__ We,
    const float* __restrict__ be, const float* __restrict__ Wd,
    const float* __restrict__ bd, float* __restrict__ e2,
    float* __restrict__ d2) {
    const int blk = blockIdx.x;
    const int b = blk >> 3;
    const int t0 = (blk & 7) * 32;  // 0..224 over 2T
    const int tid = threadIdx.x;    // output col

    __shared__ float hl[32][HH];
    for (int idx = tid; idx < 32 * 64; idx += 256) {
        int r = idx >> 6, q = idx & 63;
        ((float4*)hl[r])[q] =
            ((const float4*)(hs + ((size_t)b * 2 * TT + t0 + r) * HH))[q];
    }
    __syncthreads();

    const bool enc = t0 < TT;
    const float* W = enc ? We : Wd;
    const float bias = enc ? be[tid] : bd[tid];

    float acc[32];
#pragma unroll
    for (int r = 0; r < 32; ++r) acc[r] = 0.f;

    const float4* w4 = (const float4*)(W + tid * HH);
    for (int k4 = 0; k4 < 64; ++k4) {
        float4 wv = w4[k4];
#pragma unroll
        for (int r = 0; r < 32; ++r) {
            float4 hv = ((const float4*)hl[r])[k4];  // broadcast read
            acc[r] = fmaf(wv.x, hv.x, acc[r]);
            acc[r] = fmaf(wv.y, hv.y, acc[r]);
            acc[r] = fmaf(wv.z, hv.z, acc[r]);
            acc[r] = fmaf(wv.w, hv.w, acc[r]);
        }
    }

    float* out = enc ? (e2 + ((size_t)b * TT + t0) * HH)
                     : (d2 + ((size_t)b * TT + (t0 - TT)) * HH);
#pragma unroll
    for (int r = 0; r < 32; ++r) out[r * HH + tid] = acc[r] + bias;
}

// ---------------------------------------------------------------------------
// Attention scores: p = tanh(e2_j + d2_i) . v  for a 32x32 (i,j) tile.
// grid = 512 = b(32) x it(4) x jt(4); block = 256; 4x i-register-blocked.
// ---------------------------------------------------------------------------
#define EPAD 260  // float4-aligned LDS row stride
__global__ __launch_bounds__(256) void attn_p_kernel(
    const float* __restrict__ e2, const float* __restrict__ d2,
    const float* __restrict__ vv, float* __restrict__ p_ws) {
    __shared__ float e2c[32][EPAD];
    __shared__ float d2t[32][EPAD];
    __shared__ float v_lds[HH];

    const int blk = blockIdx.x;
    const int b = blk >> 4;
    const int i0 = ((blk >> 2) & 3) * 32;
    const int j0 = (blk & 3) * 32;
    const int tid = threadIdx.x;
    const int jl = tid & 31, ig = tid >> 5;

    if (tid < 64) *(float4*)&v_lds[tid * 4] = ((const float4*)vv)[tid];
    for (int idx = tid; idx < 32 * 64; idx += 256) {
        int r = idx >> 6, q = idx & 63;
        *(float4*)&d2t[r][q * 4] = ((const float4*)(d2 + (b * TT + i0 + r) * HH))[q];
        *(float4*)&e2c[r][q * 4] = ((const float4*)(e2 + (b * TT + j0 + r) * HH))[q];
    }
    __syncthreads();

    float a0 = 0.f, a1 = 0.f, a2 = 0.f, a3 = 0.f;
    for (int h = 0; h < HH; h += 4) {
        float4 ev = *(const float4*)&e2c[jl][h];
        float4 vx = *(const float4*)&v_lds[h];
        float4 d0 = *(const float4*)&d2t[ig * 4 + 0][h];
        float4 d1 = *(const float4*)&d2t[ig * 4 + 1][h];
        float4 d2v = *(const float4*)&d2t[ig * 4 + 2][h];
        float4 d3 = *(const float4*)&d2t[ig * 4 + 3][h];
        a0 = fmaf(tanh_f(ev.x + d0.x), vx.x, a0);
        a0 = fmaf(tanh_f(ev.y + d0.y), vx.y, a0);
        a0 = fmaf(tanh_f(ev.z + d0.z), vx.z, a0);
        a0 = fmaf(tanh_f(ev.w + d0.w), vx.w, a0);
        a1 = fmaf(tanh_f(ev.x + d1.x), vx.x, a1);
        a1 = fmaf(tanh_f(ev.y + d1.y), vx.y, a1);
        a1 = fmaf(tanh_f(ev.z + d1.z), vx.z, a1);
        a1 = fmaf(tanh_f(ev.w + d1.w), vx.w, a1);
        a2 = fmaf(tanh_f(ev.x + d2v.x), vx.x, a2);
        a2 = fmaf(tanh_f(ev.y + d2v.y), vx.y, a2);
        a2 = fmaf(tanh_f(ev.z + d2v.z), vx.z, a2);
        a2 = fmaf(tanh_f(ev.w + d2v.w), vx.w, a2);
        a3 = fmaf(tanh_f(ev.x + d3.x), vx.x, a3);
        a3 = fmaf(tanh_f(ev.y + d3.y), vx.y, a3);
        a3 = fmaf(tanh_f(ev.z + d3.z), vx.z, a3);
        a3 = fmaf(tanh_f(ev.w + d3.w), vx.w, a3);
    }
    float* pr = p_ws + (b * TT + i0 + ig * 4) * TT + j0 + jl;
    pr[0 * TT] = a0;
    pr[1 * TT] = a1;
    pr[2 * TT] = a2;
    pr[3 * TT] = a3;
}

// ---------------------------------------------------------------------------
// Softmax over j with mask (memory-bound finisher).
// grid = 256 = b(32) x 8 row-tiles (16 rows); block = 256 (16 rows x 16 lanes).
// ---------------------------------------------------------------------------
__global__ __launch_bounds__(256) void attn_sm_kernel(
    const float* __restrict__ p_ws, const float* __restrict__ seq,
    float* __restrict__ out) {
    const int blk = blockIdx.x;
    const int b = blk >> 3;
    const int r0 = (blk & 7) * 16;
    const int tid = threadIdx.x;
    const int r = tid >> 4, l16 = tid & 15;
    const int row = (b * TT + r0 + r) * TT;

    float xr[8];
    float m = -1e30f;
#pragma unroll
    for (int k = 0; k < 8; ++k) {
        const int j = l16 + 16 * k;
        float x = p_ws[row + j];
        float sv = (j == 0) ? 0.1f : seq[b * TT + j];
        if (sv == 0.f) x -= 1000.f;
        xr[k] = x;
        m = fmaxf(m, x);
    }
#pragma unroll
    for (int o = 8; o >= 1; o >>= 1) m = fmaxf(m, __shfl_xor(m, o));
    float s = 0.f;
#pragma unroll
    for (int k = 0; k < 8; ++k) {
        xr[k] = __expf(xr[k] - m);
        s += xr[k];
    }
#pragma unroll
    for (int o = 8; o >= 1; o >>= 1) s += __shfl_xor(s, o);
    float inv = rcp_f(s);
#pragma unroll
    for (int k = 0; k < 8; ++k) out[row + l16 + 16 * k] = xr[k] * inv;
}

// ---------------------------------------------------------------------------
extern "C" void kernel_launch(void* const* d_in, const int* in_sizes, int n_in,
                              void* d_out, int out_size, void* d_ws, size_t ws_size,
                              hipStream_t stream) {
    const float* seq = (const float*)d_in[0];
    const int* seq_m = (const int*)d_in[1];
    const float* target = (const float*)d_in[2];
    const float* Wih_e = (const float*)d_in[3];
    const float* Whh_e = (const float*)d_in[4];
    const float* bih_e = (const float*)d_in[5];
    const float* bhh_e = (const float*)d_in[6];
    const float* Wih_d = (const float*)d_in[7];
    const float* Whh_d = (const float*)d_in[8];
    const float* bih_d = (const float*)d_in[9];
    const float* bhh_d = (const float*)d_in[10];
    const float* We = (const float*)d_in[11];
    const float* be = (const float*)d_in[12];
    const float* Wd = (const float*)d_in[13];
    const float* bd = (const float*)d_in[14];
    const float* vv = (const float*)d_in[15];

    float* ws = (float*)d_ws;
    const size_t SZ_ED = (size_t)BB * TT * HH;  // 1,048,576 floats
    float* e2 = ws;
    float* d2 = e2 + SZ_ED;
    float* hs = d2 + SZ_ED;   // [B][2T][H] = 2*SZ_ED floats
    float* p_ws = hs;         // alias: hs dead after proj; attn_p then writes p

    const size_t needed = 4 * SZ_ED * sizeof(float);  // 16 MB
    if (ws_size < needed) return;

    lstm_kernel<<<BB, 1024, 0, stream>>>(seq, seq_m, target, Wih_e, Whh_e, bih_e,
                                         bhh_e, Wih_d, Whh_d, bih_d, bhh_d, hs);
    proj_kernel<<<256, 256, 0, stream>>>(hs, We, be, Wd, bd, e2, d2);
    attn_p_kernel<<<512, 256, 0, stream>>>(e2, d2, vv, p_ws);
    attn_sm_kernel<<<256, 256, 0, stream>>>(p_ws, seq, (float*)d_out);
}

// Round 9
// 598.380 us; speedup vs baseline: 14.6970x; 14.6970x over previous
//
#include <hip/hip_runtime.h>
#include <hip/hip_bf16.h>

// Problem constants
#define BB 32    // batch
#define TT 128   // T_E == T_D
#define HH 256   // hidden
#define G4 4     // blocks per batch for LSTM
#define UPB 64   // units per LSTM slice (256/4)
#define RPB 256  // gate rows per LSTM slice (4 gates * 64 units)

#define AGENT __HIP_MEMORY_SCOPE_AGENT
#define AL(p) __hip_atomic_load((p), __ATOMIC_RELAXED, AGENT)

__device__ __forceinline__ float rcp_f(float x) { return __builtin_amdgcn_rcpf(x); }
__device__ __forceinline__ float sigmoid_f(float x) {
    return rcp_f(1.f + __expf(-x));  // ~1e-7 rel err vs 7e-3 threshold
}
__device__ __forceinline__ float tanh_f(float x) {
    float e = __expf(2.f * x);
    return 1.f - 2.f * rcp_f(e + 1.f);
}

// ---------------------------------------------------------------------------
// LSTM + fused projections — R24 = RESTORED R15 (best measured: lstm 484us,
// total 599-602us across three runs R0/R4/R19).
// grid = 128 (blk = g*32 + b); block = 512 = 8 waves.
// Waves 0-7: gate dot; wave 0: serial act+publish; waves 1-3: ring poll;
// waves 4-7: e2/d2 proj row t-1 from double-buffered hbuf.
//
// FULL SESSION LEDGER (why this is the practical floor):
//   R12 545 | R13 pw[runtime] scratch 1449 | R14 rotated-addr 645
//   R15 484 (THIS) | R16 lgkm-only barriers NULL (vmcnt drain off-path)
//   R17 gate-colocation 706 (act on every wave's path)
//   R18 pk_fma 589 (no f32 pk-rate on gfx950; asm broke scheduling)
//   R19 XCD-coloring NULL (RTT placement-invariant)
//   R20 k-split partial exchange 658 (12x write volume, WRITE 419MB)
//   R21 1-CU stream-from-L2 1923 (per-CU load BW wall, VALU 3.4%)
//   R22 1-CU w[64]/thread 6338 (scratch spill: VGPR=64, WRITE 214MB)
//   R23 1-CU 4x16 arrays 8794 (remat: VGPR=64, FETCH 2.9GB/dispatch)
// Structure: serial chain = 256 x (cross-block store->poll RTT ~2700cy +
// dot/act ~1800cy). HBM 1.3%, VALU 16%, latency-bound. Micro-edits null,
// slot additions regress, alternative decompositions all worse. hipcc will
// not hold >128 weight VGPRs live across a barriered recurrence loop
// (R22/R23), so the zero-RTT single-CU design is unreachable at HIP level.
// ---------------------------------------------------------------------------
__global__ __launch_bounds__(512, 2) void lstm_kernel(
    const float* __restrict__ seq,     // [B][128]
    const int* __restrict__ seq_m,     // [B]
    const float* __restrict__ target,  // [B][128]
    const float* __restrict__ Wih_e,   // [1024]
    const float* __restrict__ Whh_e,   // [1024][256]
    const float* __restrict__ bih_e, const float* __restrict__ bhh_e,
    const float* __restrict__ Wih_d, const float* __restrict__ Whh_d,
    const float* __restrict__ bih_d, const float* __restrict__ bhh_d,
    const float* __restrict__ We, const float* __restrict__ be,
    const float* __restrict__ Wd, const float* __restrict__ bd,
    float* __restrict__ e2,  // [B][128][256]
    float* __restrict__ d2,  // [B][128][256]
    unsigned long long* __restrict__ mbox,   // [2][B][256] tagged h packets
    unsigned long long* __restrict__ hsave)  // [B][256] tag-1 enc state @ last
{
    const int blk = blockIdx.x;
    const int b = blk & 31;   // batch
    const int g = blk >> 5;   // slice 0..3
    const int tid = threadIdx.x;
    const int row_local = tid >> 1;  // 0..255
    const int half = tid & 1;        // k-half
    const int gate = row_local >> 6; // 0..3 (i,f,g,o)
    const int u_local = row_local & 63;
    const int row_global = gate * HH + g * UPB + u_local;
    const int last = seq_m[b] - 1;
    // proj role (waves 4-7): s in [0,256); col g*64+(s>>2); k-quarter s&3
    const int s = tid - 256;
    const int pu = s >> 2;
    const int kq = s & 3;
    const int pcol = g * UPB + pu;

    __shared__ float hbuf[2][HH];   // double-buffered h (phase1 reads ^1)
    __shared__ float g_lds[RPB];
    __shared__ float x_lds[2 * TT];
    __shared__ float h_final[HH];   // boundary h vector (rows 127)

    for (int i = tid; i < TT; i += 512) {
        x_lds[i] = seq[b * TT + i];
        x_lds[TT + i] = target[b * TT + i];
    }

    float4 w[32];
    float bias_r, wih_r;
    auto loadw = [&](const float* Whh, const float* Wih,
                     const float* bih, const float* bhh) {
        const float4* wr = (const float4*)(Whh + row_global * HH + half * 128);
#pragma unroll
        for (int i = 0; i < 32; ++i) w[i] = wr[i];
        bias_r = bih[row_global] + bhh[row_global];
        wih_r = Wih[row_global];
    };
    loadw(Whh_e, Wih_e, bih_e, bhh_e);

    float4 pw[16];
    float pb = 0.f;
    auto loadp = [&](const float* W, const float* bias) {
        const float4* src = (const float4*)(W + pcol * HH + kq * 64);
#pragma unroll
        for (int i = 0; i < 16; ++i) pw[i] = src[i];
        pb = bias[pcol];
    };
    if (tid >= 256) loadp(We, be);

    // plain proj dot: static offsets, no extra address VALU (R12-proven)
    auto projdot = [&](const float* hsrc) -> float {
        const float4* hp = (const float4*)(hsrc + kq * 64);
        float pa = 0.f;
#pragma unroll
        for (int i = 0; i < 16; ++i) {
            float4 hv = hp[i];
            pa = fmaf(pw[i].x, hv.x, pa);
            pa = fmaf(pw[i].y, hv.y, pa);
            pa = fmaf(pw[i].z, hv.z, pa);
            pa = fmaf(pw[i].w, hv.w, pa);
        }
        pa += __shfl_xor(pa, 1);
        pa += __shfl_xor(pa, 2);  // 4 k-quarters combined
        return pa + pb;
    };

    if (tid < 64) {  // h(-1) = 0 lives in buffer 1
        ((float4*)hbuf[1])[tid] = make_float4(0.f, 0.f, 0.f, 0.f);
    }
    __syncthreads();

    float c = 0.f, c_saved = 0.f, h_saved = 0.f;

    for (int t = 0; t < 2 * TT; ++t) {
        const int phase = t >> 7;  // 0 = encoder, 1 = decoder
        const int tt = t & 127;
        const float x = x_lds[t];
        const int rb = (t & 1) ^ 1;  // buffer holding h(t-1)

        // ---- phase 1 (all 8 waves): gate-row dot over own 128-wide slice --
        const float4* h4 = ((const float4*)hbuf[rb]) + half * 32;
        float4 a4 = make_float4(0.f, 0.f, 0.f, 0.f);
#pragma unroll
        for (int i = 0; i < 32; ++i) {
            float4 hv = h4[i];
            a4.x = fmaf(w[i].x, hv.x, a4.x);
            a4.y = fmaf(w[i].y, hv.y, a4.y);
            a4.z = fmaf(w[i].z, hv.z, a4.z);
            a4.w = fmaf(w[i].w, hv.w, a4.w);
        }
        float acc = (a4.x + a4.y) + (a4.z + a4.w);
        acc += __shfl_xor(acc, 1);  // combine the two k-halves
        float gv = acc + bias_r + x * wih_r;  // bias/Wih folded off serial path
        if (half == 0) g_lds[row_local] = gv;
        __syncthreads();  // (A) gates visible; hbuf[t&1] free to write

        // ---- phase 2 (wave 0): minimal serial segment ----
        if (tid < 64) {
            float gi = g_lds[tid];
            float gf = g_lds[64 + tid];
            float gg = g_lds[128 + tid];
            float go = g_lds[192 + tid];
            float si = sigmoid_f(gi);
            float sf = sigmoid_f(gf);
            float tg = tanh_f(gg);
            float so = sigmoid_f(go);
            c = sf * c + si * tg;
            float h = so * tanh_f(c);
            const int ug = g * UPB + tid;
            // publish FIRST: the only VMEM op on wave 0's pre-barrier drain
            unsigned long long pkt =
                ((unsigned long long)(unsigned)(t + 1) << 32) | __float_as_uint(h);
            __hip_atomic_store(&mbox[(t & 1) * BB * HH + b * HH + ug], pkt,
                               __ATOMIC_RELAXED, AGENT);
            if (phase == 0 && tt == last) {
                c_saved = c;
                h_saved = h;
                unsigned long long spkt =
                    (1ull << 32) | (unsigned long long)__float_as_uint(h);
                __hip_atomic_store(&hsave[b * HH + ug], spkt, __ATOMIC_RELAXED, AGENT);
            }
            hbuf[t & 1][ug] = (t == TT - 1) ? h_saved : h;
        }

        // ---- phase 3 (waves 1..3): ring poll of partners' tagged h ----
        if (tid >= 64 && tid < 256) {
            const int p = (g + (tid >> 6)) & 3;  // partner slice 1..3 away
            const int lane = tid & 63;
            const int ppu = p * UPB + lane;
            unsigned long long* src;
            unsigned want;
            if (t == TT - 1) {
                src = &hsave[b * HH + ppu];
                want = 1u;
            } else {
                src = &mbox[(t & 1) * BB * HH + b * HH + ppu];
                want = (unsigned)(t + 1);
            }
            unsigned long long pv;
            {
                unsigned long long r0 = AL(src);
                unsigned long long r1 = AL(src);
                unsigned long long r2 = AL(src);
                unsigned long long r3 = AL(src);
                for (;;) {
                    if ((unsigned)(r0 >> 32) == want) { pv = r0; break; }
                    r0 = AL(src);
                    if ((unsigned)(r1 >> 32) == want) { pv = r1; break; }
                    r1 = AL(src);
                    if ((unsigned)(r2 >> 32) == want) { pv = r2; break; }
                    r2 = AL(src);
                    if ((unsigned)(r3 >> 32) == want) { pv = r3; break; }
                    r3 = AL(src);
                }
            }
            hbuf[t & 1][ppu] = __uint_as_float((unsigned)pv);
        }

        // ---- proj (waves 4..7): e2/d2 row t-1, hidden in the poll window --
        if (tid >= 256 && t >= 1) {
            const float* hsrc = (t == TT) ? h_final : hbuf[rb];
            float pv = projdot(hsrc);
            if (kq == 0) {
                if (t <= TT)
                    e2[(b * TT + (t - 1)) * HH + pcol] = pv;
                else
                    d2[(b * TT + (t - 1 - TT)) * HH + pcol] = pv;
            }
        }
        // at the enc boundary, recover full h(TT-1) (tag TT) into h_final
        if (tid >= 256 && t == TT - 1) {
            unsigned long long* src = &mbox[((TT - 1) & 1) * BB * HH + b * HH + s];
            const unsigned want = (unsigned)TT;
            unsigned long long r0 = AL(src);
            unsigned long long r1 = AL(src);
            unsigned long long pv;
            for (;;) {
                if ((unsigned)(r0 >> 32) == want) { pv = r0; break; }
                r0 = AL(src);
                if ((unsigned)(r1 >> 32) == want) { pv = r1; break; }
                r1 = AL(src);
            }
            h_final[s] = __uint_as_float((unsigned)pv);
        }
        if (tid >= 256 && t == TT) loadp(Wd, bd);

        __syncthreads();  // (B) hbuf[t&1] complete for next step

        if (t == TT - 1) {  // encoder -> decoder transition
            loadw(Whh_d, Wih_d, bih_d, bhh_d);
            c = c_saved;
        }
    }

    // ---- post-loop: d2 row TT-1 from h(2TT-1) (tag 2TT) ----
    if (tid >= 256) {
        unsigned long long* src = &mbox[((2 * TT - 1) & 1) * BB * HH + b * HH + s];
        const unsigned want = (unsigned)(2 * TT);
        unsigned long long r0 = AL(src);
        unsigned long long r1 = AL(src);
        unsigned long long pv;
        for (;;) {
            if ((unsigned)(r0 >> 32) == want) { pv = r0; break; }
            r0 = AL(src);
            if ((unsigned)(r1 >> 32) == want) { pv = r1; break; }
            r1 = AL(src);
        }
        h_final[s] = __uint_as_float((unsigned)pv);
    }
    __syncthreads();
    if (tid >= 256) {
        float pv = projdot(h_final);
        if (kq == 0) d2[(b * TT + (TT - 1)) * HH + pcol] = pv;
    }
}

// ---------------------------------------------------------------------------
// Attention scores: p = tanh(e2_j + d2_i) . v  for a 32x32 (i,j) tile.
// grid = 512 = b(32) x it(4) x jt(4); block = 256; 4x i-register-blocked.
// ---------------------------------------------------------------------------
#define EPAD 260  // float4-aligned LDS row stride
__global__ __launch_bounds__(256) void attn_p_kernel(
    const float* __restrict__ e2, const float* __restrict__ d2,
    const float* __restrict__ vv, float* __restrict__ p_ws) {
    __shared__ float e2c[32][EPAD];
    __shared__ float d2t[32][EPAD];
    __shared__ float v_lds[HH];

    const int blk = blockIdx.x;
    const int b = blk >> 4;
    const int i0 = ((blk >> 2) & 3) * 32;
    const int j0 = (blk & 3) * 32;
    const int tid = threadIdx.x;
    const int jl = tid & 31, ig = tid >> 5;

    if (tid < 64) *(float4*)&v_lds[tid * 4] = ((const float4*)vv)[tid];
    for (int idx = tid; idx < 32 * 64; idx += 256) {
        int r = idx >> 6, q = idx & 63;
        *(float4*)&d2t[r][q * 4] = ((const float4*)(d2 + (b * TT + i0 + r) * HH))[q];
        *(float4*)&e2c[r][q * 4] = ((const float4*)(e2 + (b * TT + j0 + r) * HH))[q];
    }
    __syncthreads();

    float a0 = 0.f, a1 = 0.f, a2 = 0.f, a3 = 0.f;
    for (int h = 0; h < HH; h += 4) {
        float4 ev = *(const float4*)&e2c[jl][h];
        float4 vx = *(const float4*)&v_lds[h];
        float4 d0 = *(const float4*)&d2t[ig * 4 + 0][h];
        float4 d1 = *(const float4*)&d2t[ig * 4 + 1][h];
        float4 d2v = *(const float4*)&d2t[ig * 4 + 2][h];
        float4 d3 = *(const float4*)&d2t[ig * 4 + 3][h];
        a0 = fmaf(tanh_f(ev.x + d0.x), vx.x, a0);
        a0 = fmaf(tanh_f(ev.y + d0.y), vx.y, a0);
        a0 = fmaf(tanh_f(ev.z + d0.z), vx.z, a0);
        a0 = fmaf(tanh_f(ev.w + d0.w), vx.w, a0);
        a1 = fmaf(tanh_f(ev.x + d1.x), vx.x, a1);
        a1 = fmaf(tanh_f(ev.y + d1.y), vx.y, a1);
        a1 = fmaf(tanh_f(ev.z + d1.z), vx.z, a1);
        a1 = fmaf(tanh_f(ev.w + d1.w), vx.w, a1);
        a2 = fmaf(tanh_f(ev.x + d2v.x), vx.x, a2);
        a2 = fmaf(tanh_f(ev.y + d2v.y), vx.y, a2);
        a2 = fmaf(tanh_f(ev.z + d2v.z), vx.z, a2);
        a2 = fmaf(tanh_f(ev.w + d2v.w), vx.w, a2);
        a3 = fmaf(tanh_f(ev.x + d3.x), vx.x, a3);
        a3 = fmaf(tanh_f(ev.y + d3.y), vx.y, a3);
        a3 = fmaf(tanh_f(ev.z + d3.z), vx.z, a3);
        a3 = fmaf(tanh_f(ev.w + d3.w), vx.w, a3);
    }
    float* pr = p_ws + (b * TT + i0 + ig * 4) * TT + j0 + jl;
    pr[0 * TT] = a0;
    pr[1 * TT] = a1;
    pr[2 * TT] = a2;
    pr[3 * TT] = a3;
}

// ---------------------------------------------------------------------------
// Softmax over j with mask (memory-bound finisher).
// grid = 256 = b(32) x 8 row-tiles (16 rows); block = 256 (16 rows x 16 lanes).
// ---------------------------------------------------------------------------
__global__ __launch_bounds__(256) void attn_sm_kernel(
    const float* __restrict__ p_ws, const float* __restrict__ seq,
    float* __restrict__ out) {
    const int blk = blockIdx.x;
    const int b = blk >> 3;
    const int r0 = (blk & 7) * 16;
    const int tid = threadIdx.x;
    const int r = tid >> 4, l16 = tid & 15;
    const int row = (b * TT + r0 + r) * TT;

    float xr[8];
    float m = -1e30f;
#pragma unroll
    for (int k = 0; k < 8; ++k) {
        const int j = l16 + 16 * k;
        float x = p_ws[row + j];
        float sv = (j == 0) ? 0.1f : seq[b * TT + j];
        if (sv == 0.f) x -= 1000.f;
        xr[k] = x;
        m = fmaxf(m, x);
    }
#pragma unroll
    for (int o = 8; o >= 1; o >>= 1) m = fmaxf(m, __shfl_xor(m, o));
    float s = 0.f;
#pragma unroll
    for (int k = 0; k < 8; ++k) {
        xr[k] = __expf(xr[k] - m);
        s += xr[k];
    }
#pragma unroll
    for (int o = 8; o >= 1; o >>= 1) s += __shfl_xor(s, o);
    float inv = rcp_f(s);
#pragma unroll
    for (int k = 0; k < 8; ++k) out[row + l16 + 16 * k] = xr[k] * inv;
}

// ---------------------------------------------------------------------------
extern "C" void kernel_launch(void* const* d_in, const int* in_sizes, int n_in,
                              void* d_out, int out_size, void* d_ws, size_t ws_size,
                              hipStream_t stream) {
    const float* seq = (const float*)d_in[0];
    const int* seq_m = (const int*)d_in[1];
    const float* target = (const float*)d_in[2];
    const float* Wih_e = (const float*)d_in[3];
    const float* Whh_e = (const float*)d_in[4];
    const float* bih_e = (const float*)d_in[5];
    const float* bhh_e = (const float*)d_in[6];
    const float* Wih_d = (const float*)d_in[7];
    const float* Whh_d = (const float*)d_in[8];
    const float* bih_d = (const float*)d_in[9];
    const float* bhh_d = (const float*)d_in[10];
    const float* We = (const float*)d_in[11];
    const float* be = (const float*)d_in[12];
    const float* Wd = (const float*)d_in[13];
    const float* bd = (const float*)d_in[14];
    const float* vv = (const float*)d_in[15];

    float* ws = (float*)d_ws;
    const size_t SZ_ED = (size_t)BB * TT * HH;  // 1,048,576 floats
    float* e2 = ws;
    float* d2 = e2 + SZ_ED;
    float* p_ws = d2 + SZ_ED;                               // [B][128][128]
    unsigned long long* mbox =
        (unsigned long long*)(p_ws + (size_t)BB * TT * TT);  // [2][B][H]
    unsigned long long* hsave = mbox + 2 * BB * HH;          // [B][H]

    const size_t needed = (2 * SZ_ED + (size_t)BB * TT * TT) * sizeof(float) +
                          3 * BB * HH * sizeof(unsigned long long);
    if (ws_size < needed) return;

    hipMemsetAsync(mbox, 0, 3 * BB * HH * sizeof(unsigned long long), stream);
    lstm_kernel<<<BB * G4, 512, 0, stream>>>(seq, seq_m, target, Wih_e, Whh_e, bih_e,
                                             bhh_e, Wih_d, Whh_d, bih_d, bhh_d, We,
                                             be, Wd, bd, e2, d2, mbox, hsave);
    attn_p_kernel<<<512, 256, 0, stream>>>(e2, d2, vv, p_ws);
    attn_sm_kernel<<<256, 256, 0, stream>>>(p_ws, seq, (float*)d_out);
}